// Round 1
// baseline (266.072 us; speedup 1.0000x reference)
//
#include <hip/hip_runtime.h>
#include <math.h>

// RBF_Conv2d cdist: x (B,3,224,224) f32, weight (64,75) f32 -> out (B,64,224,224) f32
// dist[b,o,y,x] = || window(b,:,y,x) - weight[o,:] ||_2

#define KH 5
#define KW 5
#define PAD 2
#define CH 3
#define DD 75          // CH*KH*KW
#define OC 64
#define HH 224
#define WW 224
#define HW (HH * WW)

// Precompute ||w_o||^2 into workspace (64 floats).
__global__ __launch_bounds__(64) void wn_kernel(const float* __restrict__ w,
                                                float* __restrict__ wn) {
    int o = threadIdx.x;
    float s = 0.f;
#pragma unroll
    for (int d = 0; d < DD; ++d) {
        float v = w[o * DD + d];
        s = fmaf(v, v, s);
    }
    wn[o] = s;
}

__global__ __launch_bounds__(256) void rbf_kernel(const float* __restrict__ x,
                                                  const float* __restrict__ w,
                                                  const float* __restrict__ wn,
                                                  float* __restrict__ out) {
    int p = blockIdx.x * 256 + threadIdx.x;   // pixel id; grid sized exactly
    int xc = p % WW;
    int t  = p / WW;
    int yc = t % HH;
    int b  = t / HH;

    const float* xb = x + (size_t)b * (CH * HW);

    // Load 5x5x3 window into registers (zero-padded), accumulate ||p||^2.
    float win[DD];
    float pn = 0.f;
#pragma unroll
    for (int c = 0; c < CH; ++c) {
#pragma unroll
        for (int i = 0; i < KH; ++i) {
            int yy = yc + i - PAD;
            bool yv = (unsigned)yy < (unsigned)HH;
#pragma unroll
            for (int j = 0; j < KW; ++j) {
                int xx = xc + j - PAD;
                float v = (yv && ((unsigned)xx < (unsigned)WW))
                              ? xb[(c * HH + yy) * WW + xx]
                              : 0.f;
                win[(c * KH + i) * KW + j] = v;
                pn = fmaf(v, v, pn);
            }
        }
    }

    float* ob = out + ((size_t)b * OC) * HW + (size_t)yc * WW + xc;

    // 64 prototypes, 4 at a time for ILP. Weight addresses are wave-uniform
    // -> compiler emits scalar loads (K$), keeping the VALU pipe for FMAs.
#pragma unroll 1
    for (int og = 0; og < OC; og += 4) {
        const float* wr = w + og * DD;
        float a0 = 0.f, a1 = 0.f, a2 = 0.f, a3 = 0.f;
#pragma unroll
        for (int d = 0; d < DD; ++d) {
            float v = win[d];
            a0 = fmaf(v, wr[d], a0);
            a1 = fmaf(v, wr[DD + d], a1);
            a2 = fmaf(v, wr[2 * DD + d], a2);
            a3 = fmaf(v, wr[3 * DD + d], a3);
        }
        float d0 = pn + wn[og + 0] - 2.f * a0;
        float d1 = pn + wn[og + 1] - 2.f * a1;
        float d2 = pn + wn[og + 2] - 2.f * a2;
        float d3 = pn + wn[og + 3] - 2.f * a3;
        ob[(size_t)(og + 0) * HW] = sqrtf(fmaxf(d0, 0.f));
        ob[(size_t)(og + 1) * HW] = sqrtf(fmaxf(d1, 0.f));
        ob[(size_t)(og + 2) * HW] = sqrtf(fmaxf(d2, 0.f));
        ob[(size_t)(og + 3) * HW] = sqrtf(fmaxf(d3, 0.f));
    }
}

extern "C" void kernel_launch(void* const* d_in, const int* in_sizes, int n_in,
                              void* d_out, int out_size, void* d_ws, size_t ws_size,
                              hipStream_t stream) {
    const float* x  = (const float*)d_in[0];
    const float* w  = (const float*)d_in[1];
    float* out      = (float*)d_out;
    float* wn       = (float*)d_ws;   // 64 floats of scratch

    int B    = in_sizes[0] / (CH * HW);   // 32
    int npix = B * HW;                    // 1,605,632 (divisible by 256)

    wn_kernel<<<1, 64, 0, stream>>>(w, wn);
    rbf_kernel<<<npix / 256, 256, 0, stream>>>(x, w, wn, out);
}

// Round 2
// 232.113 us; speedup vs baseline: 1.1463x; 1.1463x over previous
//
#include <hip/hip_runtime.h>
#include <math.h>

// RBF_Conv2d cdist: x (B,3,224,224) f32, weight (64,75) f32 -> out (B,64,224,224) f32
// dist[b,o,y,x] = || window(b,:,y,x) - weight[o,:] ||_2
//
// Strategy: stream the 75 window values (each loaded once, never stored),
// keep 64 accumulators live in VGPRs, weights transposed+pre-scaled (-2w)
// so the inner loop is 64 wave-uniform-scalar-operand FMAs per element.

#define KH 5
#define KW 5
#define PAD 2
#define CH 3
#define DD 75          // CH*KH*KW
#define OC 64
#define HH 224
#define WW 224
#define HW (HH * WW)

// prep: wn[o] = ||w_o||^2 ; wT[d*64+o] = -2 * w[o*75+d]
__global__ __launch_bounds__(256) void prep_kernel(const float* __restrict__ w,
                                                   float* __restrict__ wn,
                                                   float* __restrict__ wT) {
    int t = blockIdx.x * 256 + threadIdx.x;
    if (t < DD * OC) {
        int d = t >> 6, o = t & 63;
        wT[t] = -2.0f * w[o * DD + d];
    }
    if (t < OC) {
        float s = 0.f;
        for (int d = 0; d < DD; ++d) {
            float v = w[t * DD + d];
            s = fmaf(v, v, s);
        }
        wn[t] = s;
    }
}

__global__ __launch_bounds__(256) void rbf_kernel(const float* __restrict__ x,
                                                  const float* __restrict__ wn,
                                                  const float* __restrict__ wT,
                                                  float* __restrict__ out) {
    int p = blockIdx.x * 256 + threadIdx.x;   // pixel id; grid sized exactly
    int xc = p % WW;
    int t  = p / WW;
    int yc = t % HH;
    int b  = t / HH;

    const float* xb = x + (size_t)b * (CH * HW);

    float acc[OC];
#pragma unroll
    for (int o = 0; o < OC; ++o) acc[o] = 0.f;
    float pn = 0.f;

    const float* wp = wT;
    // keep c,i as runtime loops: code stays ~2.6KB (I$-friendly), j and o unrolled.
#pragma unroll 1
    for (int c = 0; c < CH; ++c) {
#pragma unroll 1
        for (int i = 0; i < KH; ++i) {
            int yy = yc + i - PAD;
            bool yv = (unsigned)yy < (unsigned)HH;
            int ycl = min(max(yy, 0), HH - 1);           // clamped (safe) address
            const float* row = xb + (c * HH + ycl) * WW;
#pragma unroll
            for (int j = 0; j < KW; ++j) {
                int xx = xc + j - PAD;
                bool ok = yv && ((unsigned)xx < (unsigned)WW);
                int xcl = min(max(xx, 0), WW - 1);
                float v = row[xcl];
                v = ok ? v : 0.f;
                pn = fmaf(v, v, pn);
                const float* wj = wp + j * OC;           // wave-uniform -> s_load
#pragma unroll
                for (int o = 0; o < OC; ++o)
                    acc[o] = fmaf(v, wj[o], acc[o]);     // v_fma_f32 acc, v, s, acc
            }
            wp += KW * OC;
        }
    }

    float* ob = out + ((size_t)b * OC) * HW + (size_t)yc * WW + xc;
#pragma unroll
    for (int o = 0; o < OC; ++o) {
        float d2 = pn + wn[o] + acc[o];                  // acc already holds -2*dot
        ob[(size_t)o * HW] = sqrtf(fmaxf(d2, 0.f));      // coalesced 256B stores
    }
}

extern "C" void kernel_launch(void* const* d_in, const int* in_sizes, int n_in,
                              void* d_out, int out_size, void* d_ws, size_t ws_size,
                              hipStream_t stream) {
    const float* x = (const float*)d_in[0];
    const float* w = (const float*)d_in[1];
    float* out     = (float*)d_out;

    float* wn = (float*)d_ws;          // 64 floats
    float* wT = (float*)d_ws + OC;     // 75*64 floats

    int B    = in_sizes[0] / (CH * HW);   // 32
    int npix = B * HW;                    // 1,605,632 (divisible by 256)

    prep_kernel<<<(DD * OC + 255) / 256, 256, 0, stream>>>(w, wn, wT);
    rbf_kernel<<<npix / 256, 256, 0, stream>>>(x, wn, wT, out);
}